// Round 11
// baseline (111.444 us; speedup 1.0000x reference)
//
#include <hip/hip_runtime.h>
#include <stdint.h>

typedef unsigned short u16;
typedef __attribute__((ext_vector_type(8))) short short8;
typedef __attribute__((ext_vector_type(4))) float f32x4;

#define MFMA __builtin_amdgcn_mfma_f32_16x16x32_bf16

__device__ __forceinline__ u16 f2bf(float f) {
  union { float f; uint32_t u; } v; v.f = f;
  return (u16)((v.u + 0x7FFFu + ((v.u >> 16) & 1u)) >> 16);
}

// ws layout (bytes)
#define WS_H    0          // u16 H[64][2][8][9][64][8]  fragment-major (9,437,184 B)
#define WS_Q1   9502720    // f32 q1[128]
#define WS_Q2   9503232    // f32 q2[128]
#define WS_M1P  9503744    // u64 m1p[64][4096]   (TRANSPOSED: [kt][row])
#define WS_M2P  11600896   // u64 m2p[64][4096]
#define WS_RS1  13698048   // f32 rs1[4096]
#define WS_RS2  13714432   // f32 rs2[4096]

#define GLOAD16(gp, lp) \
  __builtin_amdgcn_global_load_lds((const __attribute__((address_space(1))) uint32_t*)(gp), \
                                   (__attribute__((address_space(3))) uint32_t*)(lp), 16, 0, 0)

// ---------------- fused pre-kernel ----------------
// blocks 0-255: kproj (inline P1=W1@Wb1) -> fragment-major H
// blocks 256-767: kmask (8 rows/block, 512 thr)
// block 768: q1 = b1@Wb1, q2 = b2@Wb2
__global__ __launch_bounds__(512, 1) void kpre(const float* __restrict__ x,
                                               const int* __restrict__ sp,
                                               const float* __restrict__ W1,
                                               const float* __restrict__ b1,
                                               const float* __restrict__ W2,
                                               const float* __restrict__ b2,
                                               const float* __restrict__ Wb,
                                               u16* __restrict__ H,
                                               unsigned long long* __restrict__ m1p,
                                               unsigned long long* __restrict__ m2p,
                                               float* __restrict__ rs1, float* __restrict__ rs2,
                                               float* __restrict__ q1, float* __restrict__ q2) {
  const int tid = threadIdx.x;
  const int bid = blockIdx.x;

  if (bid >= 256) {
    if (bid < 768) {
      // ---- kmask: pack masks into bits (transposed [kt][row]) + row sums ----
      int wave = tid >> 6, lane = tid & 63;
      int i = (bid - 256) * 8 + wave;
      const int* rowp = sp + (size_t)i * 4096;
      int c1 = 0, c2 = 0;
      for (int w = 0; w < 64; ++w) {
        int v = rowp[w * 64 + lane];
        unsigned long long bb1 = __ballot(v <= 1);
        unsigned long long bb2 = __ballot(v == 2);
        if (lane == 0) {
          m1p[(size_t)w * 4096 + i] = bb1;
          m2p[(size_t)w * 4096 + i] = bb2;
          c1 += __popcll(bb1);
          c2 += __popcll(bb2);
        }
      }
      if (lane == 0) { rs1[i] = (float)c1; rs2[i] = (float)c2; }
    } else if (tid < 128) {
      // ---- q1/q2 ----
      float s1 = 0.f, s2 = 0.f;
      for (int k = 0; k < 128; ++k) s1 += b1[k] * Wb[k * 128 + tid];
      for (int k = 0; k < 16; ++k)  s2 += b2[k] * Wb[(128 + k) * 128 + tid];
      q1[tid] = s1; q2[tid] = s2;
    }
    return;
  }

  // ---- kproj: block = 128 rows (2 kt-slabs of batch b = bid>>5) ----
  __shared__ u16 wsb[18432];              // blocked B operand [jb][n][r] (36 KB)
  __shared__ u16 xs[128 * 136];           // W1 stage, then x rows bf16 (34.8 KB)
  __shared__ u16 hs[128 * 146];           // Wb1 blocked stage, then result staging (37.4 KB)
  const int r0 = bid * 128;
  const int b = bid >> 5;
  const int kt0 = (bid & 31) * 2;
  const int w = tid >> 6, l = tid & 63, lr = l & 15, lg = l >> 4;

  // --- phase 0: stage W1 (xs, row-major bf16) and Wb1 (hs, blocked [kb][c][r]) ---
  {
    const float* wp = W1 + ((size_t)(tid >> 2)) * 128 + (tid & 3) * 32;
    u16* wd = xs + (tid >> 2) * 136 + (tid & 3) * 32;
#pragma unroll
    for (int i = 0; i < 4; ++i) {
      f32x4 a = ((const f32x4*)wp)[i * 2];
      f32x4 bq = ((const f32x4*)wp)[i * 2 + 1];
      short8 pk;
      pk[0] = (short)f2bf(a[0]); pk[1] = (short)f2bf(a[1]);
      pk[2] = (short)f2bf(a[2]); pk[3] = (short)f2bf(a[3]);
      pk[4] = (short)f2bf(bq[0]); pk[5] = (short)f2bf(bq[1]);
      pk[6] = (short)f2bf(bq[2]); pk[7] = (short)f2bf(bq[3]);
      *(short8*)(wd + i * 8) = pk;
    }
  }
  {
    u16* wbs = hs;                        // blocked Wb1: [(k>>3)*128 + c]*8 + (k&7)
    for (int i = 0; i < 32; ++i) {
      int e = i * 512 + tid;              // (k, c) row-major 128x128
      int k = e >> 7, c = e & 127;
      wbs[(((k >> 3) * 128) + c) * 8 + (k & 7)] = f2bf(Wb[k * 128 + c]);
    }
  }
  // stage W2 cols of wsb directly (cols 128..143)
  {
    for (int i = 0; i < 4; ++i) {
      int e = i * 512 + tid;              // 2048 = 128x16
      int k = e >> 4, nn = e & 15;
      wsb[(((k >> 3) * 144) + 128 + nn) * 8 + (k & 7)] = f2bf(W2[k * 16 + nn]);
    }
  }
  __syncthreads();

  // --- phase 1: P1 = W1@Wb1 via MFMA; scatter into wsb cols 0..127 ---
  {
    f32x4 accp[8];
    f32x4 zz = {0.f, 0.f, 0.f, 0.f};
#pragma unroll
    for (int fn = 0; fn < 8; ++fn) accp[fn] = zz;
#pragma unroll
    for (int kf = 0; kf < 4; ++kf) {
      short8 af = *(const short8*)(xs + (w * 16 + lr) * 136 + kf * 32 + lg * 8);
#pragma unroll
      for (int fn = 0; fn < 8; ++fn) {
        short8 bf = *(const short8*)(hs + (((kf * 4 + lg) * 128) + fn * 16 + lr) * 8);
        accp[fn] = MFMA(af, bf, accp[fn], 0, 0, 0);
      }
    }
    __syncthreads();                      // done reading hs (Wb1)
#pragma unroll
    for (int fn = 0; fn < 8; ++fn)
#pragma unroll
      for (int g = 0; g < 4; ++g) {
        int a = w * 16 + lg * 4 + g;      // P1 row (K index)
        int c = fn * 16 + lr;             // P1 col
        wsb[(((a >> 3) * 144) + c) * 8 + (a & 7)] = f2bf(accp[fn][g]);
      }
  }
  // --- phase 2: stage x rows -> xs[128][136] bf16 (overwrites W1 stage) ---
  __syncthreads();
  {
    const float* xp = x + ((size_t)(r0 + (tid >> 2))) * 128 + (tid & 3) * 32;
    u16* xd = xs + (tid >> 2) * 136 + (tid & 3) * 32;
#pragma unroll
    for (int i = 0; i < 4; ++i) {
      f32x4 a = ((const f32x4*)xp)[i * 2];
      f32x4 bq = ((const f32x4*)xp)[i * 2 + 1];
      short8 pk;
      pk[0] = (short)f2bf(a[0]); pk[1] = (short)f2bf(a[1]);
      pk[2] = (short)f2bf(a[2]); pk[3] = (short)f2bf(a[3]);
      pk[4] = (short)f2bf(bq[0]); pk[5] = (short)f2bf(bq[1]);
      pk[6] = (short)f2bf(bq[2]); pk[7] = (short)f2bf(bq[3]);
      *(short8*)(xd + i * 8) = pk;
    }
  }
  __syncthreads();

  // --- phase 3: u1h2 = x @ [P1 | W2] ---
  f32x4 acc[9];
  f32x4 zz = {0.f, 0.f, 0.f, 0.f};
#pragma unroll
  for (int fn = 0; fn < 9; ++fn) acc[fn] = zz;
#pragma unroll
  for (int kf = 0; kf < 4; ++kf) {
    short8 af = *(const short8*)(xs + (w * 16 + lr) * 136 + kf * 32 + lg * 8);
#pragma unroll
    for (int fn = 0; fn < 9; ++fn) {
      short8 bf = *(const short8*)(wsb + (((kf * 4 + lg) * 144) + fn * 16 + lr) * 8);
      acc[fn] = MFMA(af, bf, acc[fn], 0, 0, 0);
    }
  }
  __syncthreads();
#pragma unroll
  for (int fn = 0; fn < 9; ++fn)
#pragma unroll
    for (int g = 0; g < 4; ++g)
      hs[(w * 16 + lg * 4 + g) * 146 + fn * 16 + lr] = f2bf(acc[fn][g]);
  __syncthreads();
  // fragment-major coalesced write to H (2 kt-slabs)
  for (int i = 0; i < 5; ++i) {
    int e = i * 512 + tid;
    if (e < 2304) {
      int slab = e / 1152, rem = e % 1152;
      int jbl = rem / 144, n = rem % 144;
      union { u16 s[8]; uint4 v; } pk;
#pragma unroll
      for (int r = 0; r < 8; ++r) pk.s[r] = hs[(slab * 64 + jbl * 8 + r) * 146 + n];
      int kf = jbl >> 2, lgw = jbl & 3, fn = n >> 4, lrw = n & 15;
      size_t di = ((((size_t)(kt0 + slab) * 2 + kf) * 8 + b) * 9 + fn) * 512 + (lgw * 16 + lrw) * 8;
      *(uint4*)(H + di) = pk.v;
    }
  }
}

// expand 8 mask bits (byte lgsh/8 of a 32-bit half-word) -> 8 bf16 {0,1} packed as short8
__device__ __forceinline__ short8 expand_byte(uint32_t wd, int lgsh) {
  uint32_t b = (wd >> lgsh) & 0xFFu;
  uint32_t t = b * 0x8001u;
  union { uint32_t u[4]; short8 s; } r;
  r.u[0] = (t & 0x00010001u) * 0x3F80u;
  r.u[1] = (t & 0x00040004u) * 0x0FE0u;
  r.u[2] = (t & 0x00100010u) * 0x03F8u;
  r.u[3] = (t & 0x00400040u) * 0x00FEu;
  return r.s;
}

// ---------------- kernel B1: counted-vmcnt 3-buffer pipeline (R9-verified, bf16) ----------------
__global__ __launch_bounds__(512, 4) void kb1(const u16* __restrict__ H,
                                              const char* __restrict__ M1b,
                                              const char* __restrict__ M2b,
                                              const float* __restrict__ rs1, const float* __restrict__ rs2,
                                              const float* __restrict__ q1, const float* __restrict__ q2,
                                              const float* __restrict__ Wb, const float* __restrict__ bb,
                                              float* __restrict__ out) {
  __shared__ u16 bt[3][9216];              // 3-buffered B tile (54 KB)
  __shared__ u16 mkb[3][512];              // 3-buffered mask slab (3 KB)
  __shared__ float f2pf[2][64][16];        // m2@h2 kf-partials (8 KB)
  __shared__ u16 f2s[64 * 40];             // f2 bf16, K padded to 32 (5 KB)
  __shared__ u16 wb2s[4096];               // Wb2 padded to K=32 (8 KB)

  const int tid = threadIdx.x;
  const int bid = blockIdx.x;
  const int b = bid & 7;
  const int i0 = (bid >> 3) * 64;

  const int w = tid >> 6, l = tid & 63, lr = l & 15, lg = l >> 4;
  const int g = w >> 2, c = w & 3;
  const int fm2 = w & 3, kf2 = w >> 2;
  const int lgsh = lg * 8;

  const int e0 = tid * 8, e1 = 4096 + tid * 8, e2 = 8192 + tid * 8;
  const uint32_t soff0 = b * 4608 + e0;
  const uint32_t soff1 = b * 4608 + (uint32_t)(e1 < 4608 ? e1 : 32256 + e1);
  const uint32_t soff2 = b * 4608 + 32256 + e2;
  const char* mksrc = ((tid < 32) ? M1b : M2b) + (size_t)i0 * 8 + (size_t)(tid & 31) * 16;

#define STAGE(P, BUF) { \
    const u16* hp_ = H + (size_t)(P) * 73728; \
    GLOAD16(hp_ + soff0, (char*)&bt[BUF][0] + e0 * 2); \
    GLOAD16(hp_ + soff1, (char*)&bt[BUF][0] + e1 * 2); \
    if (tid < 128) GLOAD16(hp_ + soff2, (char*)&bt[BUF][0] + e2 * 2); \
    if (tid < 64)  GLOAD16(mksrc + (size_t)(P) * 32768, (char*)&mkb[BUF][0] + tid * 16); }

  const int fA0 = (c * 2 + 0) * 512 + l * 8;
  const int fA1 = (c * 2 + 1) * 512 + l * 8;
  const int fB0 = 4608 + fA0;
  const int fB1 = 4608 + fA1;
  const int fM  = kf2 * 4608 + 8 * 512 + l * 8;

  f32x4 zz = {0.f, 0.f, 0.f, 0.f};
  f32x4 acc00 = zz, acc01 = zz, acc10 = zz, acc11 = zz;
  f32x4 acc2 = zz;

#define WAITV { if (w == 0) asm volatile("s_waitcnt vmcnt(4)" ::: "memory"); \
                else if (w == 1) asm volatile("s_waitcnt vmcnt(3)" ::: "memory"); \
                else asm volatile("s_waitcnt vmcnt(2)" ::: "memory"); }

#define COMPUTE(BUF) { \
    const u16* src_ = &bt[BUF][0]; \
    uint2 c0_ = *(const uint2*)&mkb[BUF][((g * 2 + 0) * 16 + lr) * 4]; \
    uint2 c1_ = *(const uint2*)&mkb[BUF][((g * 2 + 1) * 16 + lr) * 4]; \
    uint32_t c2_ = *(const uint32_t*)&mkb[BUF][256 + (fm2 * 16 + lr) * 4 + kf2 * 2]; \
    short8 bA0_ = *(const short8*)(src_ + fA0); \
    short8 bA1_ = *(const short8*)(src_ + fA1); \
    short8 bB0_ = *(const short8*)(src_ + fB0); \
    short8 bB1_ = *(const short8*)(src_ + fB1); \
    short8 bM_  = *(const short8*)(src_ + fM); \
    short8 e0x_ = expand_byte(c0_.x, lgsh), e0y_ = expand_byte(c0_.y, lgsh); \
    short8 e1x_ = expand_byte(c1_.x, lgsh), e1y_ = expand_byte(c1_.y, lgsh); \
    short8 e2v_ = expand_byte(c2_, lgsh); \
    __builtin_amdgcn_s_setprio(1); \
    acc00 = MFMA(e0x_, bA0_, acc00, 0, 0, 0); \
    acc01 = MFMA(e0x_, bA1_, acc01, 0, 0, 0); \
    acc00 = MFMA(e0y_, bB0_, acc00, 0, 0, 0); \
    acc01 = MFMA(e0y_, bB1_, acc01, 0, 0, 0); \
    acc10 = MFMA(e1x_, bA0_, acc10, 0, 0, 0); \
    acc11 = MFMA(e1x_, bA1_, acc11, 0, 0, 0); \
    acc10 = MFMA(e1y_, bB0_, acc10, 0, 0, 0); \
    acc11 = MFMA(e1y_, bB1_, acc11, 0, 0, 0); \
    acc2  = MFMA(e2v_, bM_, acc2, 0, 0, 0); \
    __builtin_amdgcn_s_setprio(0); }

#define PHASE(P, BUF, BUF2) { WAITV; __builtin_amdgcn_s_barrier(); \
    STAGE((P) + 2, BUF2); COMPUTE(BUF) }

  // prologue: stage kt=0,1
  STAGE(0, 0);
  STAGE(1, 1);

  // stage Wb2 (overlaps prologue latency)
#pragma unroll
  for (int i = 0; i < 8; ++i) {
    int e = i * 512 + tid;
    int r_ = e & 7, nn = (e >> 3) & 127, jb = e >> 10;
    int k = jb * 8 + r_;
    wb2s[e] = f2bf((k < 16) ? Wb[(128 + k) * 128 + nn] : 0.f);
  }

  for (int p = 0; p < 60; p += 3) {
    PHASE(p, 0, 2);
    PHASE(p + 1, 1, 0);
    PHASE(p + 2, 2, 1);
  }
  PHASE(60, 0, 2);
  PHASE(61, 1, 0);
  { WAITV; __builtin_amdgcn_s_barrier(); COMPUTE(2) }                          // phase 62
  { asm volatile("s_waitcnt vmcnt(0)" ::: "memory");
    __builtin_amdgcn_s_barrier(); COMPUTE(0) }                                 // phase 63

  // epilogue: combine m2 kf-partials -> f2 bf16 tile
#pragma unroll
  for (int gg = 0; gg < 4; ++gg)
    f2pf[kf2][fm2 * 16 + lg * 4 + gg][lr] = acc2[gg];
  __syncthreads();
#pragma unroll
  for (int j = 0; j < 2; ++j) {
    int e = j * 512 + tid;
    int row = e >> 4, col = e & 15;
    f2s[row * 40 + col] = f2bf(f2pf[0][row][col] + f2pf[1][row][col]);
    f2s[row * 40 + 16 + col] = 0;
  }
  __syncthreads();

  // epilogue MFMA: acc[i][fj] += f2frag(fm=2g+i) x Wb2frag(fn=2c+fj)
  short8 bw0 = *(const short8*)(wb2s + ((lg * 128) + (c * 2 + 0) * 16 + lr) * 8);
  short8 bw1 = *(const short8*)(wb2s + ((lg * 128) + (c * 2 + 1) * 16 + lr) * 8);
  {
    short8 af0 = *(const short8*)(f2s + ((g * 2 + 0) * 16 + lr) * 40 + lg * 8);
    short8 af1 = *(const short8*)(f2s + ((g * 2 + 1) * 16 + lr) * 40 + lg * 8);
    acc00 = MFMA(af0, bw0, acc00, 0, 0, 0);
    acc01 = MFMA(af0, bw1, acc01, 0, 0, 0);
    acc10 = MFMA(af1, bw0, acc10, 0, 0, 0);
    acc11 = MFMA(af1, bw1, acc11, 0, 0, 0);
  }

  // final: + rs1*q1 + rs2*q2 + bb, store f32
  const int col0 = (c * 2 + 0) * 16 + lr, col1 = (c * 2 + 1) * 16 + lr;
  const float q10 = q1[col0], q20 = q2[col0], bb0 = bb[col0];
  const float q11 = q1[col1], q21 = q2[col1], bb1 = bb[col1];
#pragma unroll
  for (int i = 0; i < 2; ++i) {
    f32x4 a0 = i ? acc10 : acc00;
    f32x4 a1 = i ? acc11 : acc01;
#pragma unroll
    for (int gg = 0; gg < 4; ++gg) {
      int row = (g * 2 + i) * 16 + lg * 4 + gg;
      float r1 = rs1[i0 + row], r2 = rs2[i0 + row];
      size_t obase = ((size_t)b * 4096 + i0 + row) * 128;
      out[obase + col0] = a0[gg] + r1 * q10 + r2 * q20 + bb0;
      out[obase + col1] = a1[gg] + r1 * q11 + r2 * q21 + bb1;
    }
  }
}

extern "C" void kernel_launch(void* const* d_in, const int* in_sizes, int n_in,
                              void* d_out, int out_size, void* d_ws, size_t ws_size,
                              hipStream_t stream) {
  const float* x  = (const float*)d_in[0];
  const int*   sp = (const int*)d_in[1];
  const float* W1 = (const float*)d_in[2];
  const float* b1 = (const float*)d_in[3];
  const float* W2 = (const float*)d_in[4];
  const float* b2 = (const float*)d_in[5];
  const float* Wb = (const float*)d_in[6];
  const float* bb = (const float*)d_in[7];
  float* out = (float*)d_out;
  char* ws = (char*)d_ws;

  u16* H = (u16*)(ws + WS_H);
  float* q1 = (float*)(ws + WS_Q1);
  float* q2 = (float*)(ws + WS_Q2);
  unsigned long long* m1p = (unsigned long long*)(ws + WS_M1P);
  unsigned long long* m2p = (unsigned long long*)(ws + WS_M2P);
  float* rs1 = (float*)(ws + WS_RS1);
  float* rs2 = (float*)(ws + WS_RS2);

  kpre<<<769, 512, 0, stream>>>(x, sp, W1, b1, W2, b2, Wb, H, m1p, m2p, rs1, rs2, q1, q2);
  kb1<<<512, 512, 0, stream>>>(H, (const char*)m1p, (const char*)m2p,
                               rs1, rs2, q1, q2, Wb, bb, out);
}

// Round 12
// 92.818 us; speedup vs baseline: 1.2007x; 1.2007x over previous
//
#include <hip/hip_runtime.h>
#include <stdint.h>

typedef unsigned short u16;
typedef __attribute__((ext_vector_type(8))) short short8;
typedef __attribute__((ext_vector_type(4))) float f32x4;

#define MFMA __builtin_amdgcn_mfma_f32_16x16x32_bf16

__device__ __forceinline__ u16 f2bf(float f) {
  union { float f; uint32_t u; } v; v.f = f;
  return (u16)((v.u + 0x7FFFu + ((v.u >> 16) & 1u)) >> 16);
}

#define GLOAD16(gp, lp) \
  __builtin_amdgcn_global_load_lds((const __attribute__((address_space(1))) uint32_t*)(gp), \
                                   (__attribute__((address_space(3))) uint32_t*)(lp), 16, 0, 0)

// ws layout (bytes)
#define WS_H    0          // u16 H[64][2][8][9][64][8]  fragment-major (9,437,184 B)
#define WS_Q1   9502720    // f32 q1[128]
#define WS_Q2   9503232    // f32 q2[128]
#define WS_M1P  9503744    // u64 m1p[64][4096]   (TRANSPOSED: [kt][row])
#define WS_M2P  11600896   // u64 m2p[64][4096]
#define WS_RS1  13698048   // f32 rs1[4096]
#define WS_RS2  13714432   // f32 rs2[4096]
#define WS_WSB  13730816   // u16 wsb[16][144][8] blocked B operand (36,864 B)

// ---------------- kernel 0: fused kmask (blocks 0-1023) + kprep (blocks 1024-1087) ----------------
__global__ __launch_bounds__(256) void k0(const int* __restrict__ sp,
                                          unsigned long long* __restrict__ m1p,
                                          unsigned long long* __restrict__ m2p,
                                          float* __restrict__ rs1, float* __restrict__ rs2,
                                          const float* __restrict__ W1, const float* __restrict__ Wb,
                                          const float* __restrict__ b1, const float* __restrict__ b2,
                                          const float* __restrict__ W2,
                                          float* __restrict__ q1, float* __restrict__ q2,
                                          u16* __restrict__ wsbg) {
  const int tid = threadIdx.x;
  if (blockIdx.x < 1024) {
    int wave = tid >> 6, lane = tid & 63;
    int i = blockIdx.x * 4 + wave;
    const int* rowp = sp + (size_t)i * 4096;
    int c1 = 0, c2 = 0;
    for (int w = 0; w < 64; ++w) {
      int v = rowp[w * 64 + lane];
      unsigned long long bb1 = __ballot(v <= 1);
      unsigned long long bb2 = __ballot(v == 2);
      if (lane == 0) {
        m1p[(size_t)w * 4096 + i] = bb1;
        m2p[(size_t)w * 4096 + i] = bb2;
        c1 += __popcll(bb1);
        c2 += __popcll(bb2);
      }
    }
    if (lane == 0) { rs1[i] = (float)c1; rs2[i] = (float)c2; }
    return;
  }
  int idx = (int)(blockIdx.x - 1024) * 256 + tid;   // 0..16383
  int a = idx >> 7, c = idx & 127;
  float acc = 0.f;
  for (int k = 0; k < 128; ++k) acc += W1[a * 128 + k] * Wb[k * 128 + c];
  wsbg[(((a >> 3) * 144) + c) * 8 + (a & 7)] = f2bf(acc);
  if (idx < 2048) {
    int k = idx >> 4, nn2 = idx & 15;
    wsbg[(((k >> 3) * 144) + 128 + nn2) * 8 + (k & 7)] = f2bf(W2[k * 16 + nn2]);
  }
  if (idx < 128) {
    float s1 = 0.f, s2 = 0.f;
    for (int k = 0; k < 128; ++k) s1 += b1[k] * Wb[k * 128 + idx];
    for (int k = 0; k < 16; ++k)  s2 += b2[k] * Wb[(128 + k) * 128 + idx];
    q1[idx] = s1; q2[idx] = s2;
  }
}

// ---------------- kernel A': u1h2 -> fragment-major H (R9-verified) ----------------
__global__ __launch_bounds__(512, 1) void kproj(const float* __restrict__ x,
                                                const u16* __restrict__ wsbg,
                                                u16* __restrict__ H) {
  __shared__ u16 wsb[18432];              // blocked B operand (36 KB)
  __shared__ u16 xs[128 * 136];           // x rows bf16 (34.8 KB)
  __shared__ u16 hs[128 * 146];           // result staging (37.4 KB)
  const int tid = threadIdx.x;
  const int bid = blockIdx.x;
  const int r0 = bid * 128;
  const int b = bid >> 5;
  const int kt0 = (bid & 31) * 2;

  {
    const int e0 = tid * 8;
    GLOAD16(wsbg + e0,         (char*)&wsb[0] + e0 * 2);
    GLOAD16(wsbg + 4096 + e0,  (char*)&wsb[0] + (4096 + e0) * 2);
    GLOAD16(wsbg + 8192 + e0,  (char*)&wsb[0] + (8192 + e0) * 2);
    GLOAD16(wsbg + 12288 + e0, (char*)&wsb[0] + (12288 + e0) * 2);
    if (tid < 256)
      GLOAD16(wsbg + 16384 + e0, (char*)&wsb[0] + (16384 + e0) * 2);
  }
  {
    const float* xp = x + ((size_t)(r0 + (tid >> 2))) * 128 + (tid & 3) * 32;
    u16* xd = xs + (tid >> 2) * 136 + (tid & 3) * 32;
#pragma unroll
    for (int i = 0; i < 4; ++i) {
      f32x4 a = ((const f32x4*)xp)[i * 2];
      f32x4 bq = ((const f32x4*)xp)[i * 2 + 1];
      short8 pk;
      pk[0] = (short)f2bf(a[0]); pk[1] = (short)f2bf(a[1]);
      pk[2] = (short)f2bf(a[2]); pk[3] = (short)f2bf(a[3]);
      pk[4] = (short)f2bf(bq[0]); pk[5] = (short)f2bf(bq[1]);
      pk[6] = (short)f2bf(bq[2]); pk[7] = (short)f2bf(bq[3]);
      *(short8*)(xd + i * 8) = pk;
    }
  }
  __syncthreads();

  const int w = tid >> 6, l = tid & 63, lr = l & 15, lg = l >> 4;
  f32x4 acc[9];
  f32x4 zz = {0.f, 0.f, 0.f, 0.f};
#pragma unroll
  for (int fn = 0; fn < 9; ++fn) acc[fn] = zz;
#pragma unroll
  for (int kf = 0; kf < 4; ++kf) {
    short8 af = *(const short8*)(xs + (w * 16 + lr) * 136 + kf * 32 + lg * 8);
#pragma unroll
    for (int fn = 0; fn < 9; ++fn) {
      short8 bf = *(const short8*)(wsb + (((kf * 4 + lg) * 144) + fn * 16 + lr) * 8);
      acc[fn] = MFMA(af, bf, acc[fn], 0, 0, 0);
    }
  }
  __syncthreads();
#pragma unroll
  for (int fn = 0; fn < 9; ++fn)
#pragma unroll
    for (int g = 0; g < 4; ++g)
      hs[(w * 16 + lg * 4 + g) * 146 + fn * 16 + lr] = f2bf(acc[fn][g]);
  __syncthreads();
  for (int i = 0; i < 5; ++i) {
    int e = i * 512 + tid;
    if (e < 2304) {
      int slab = e / 1152, rem = e % 1152;
      int jbl = rem / 144, n = rem % 144;
      union { u16 s[8]; uint4 v; } pk;
#pragma unroll
      for (int r = 0; r < 8; ++r) pk.s[r] = hs[(slab * 64 + jbl * 8 + r) * 146 + n];
      int kf = jbl >> 2, lgw = jbl & 3, fn = n >> 4, lrw = n & 15;
      size_t di = ((((size_t)(kt0 + slab) * 2 + kf) * 8 + b) * 9 + fn) * 512 + (lgw * 16 + lrw) * 8;
      *(uint4*)(H + di) = pk.v;
    }
  }
}

// expand 8 mask bits (byte lgsh/8 of a 32-bit half-word) -> 8 bf16 {0,1} packed as short8
__device__ __forceinline__ short8 expand_byte(uint32_t wd, int lgsh) {
  uint32_t b = (wd >> lgsh) & 0xFFu;
  uint32_t t = b * 0x8001u;
  union { uint32_t u[4]; short8 s; } r;
  r.u[0] = (t & 0x00010001u) * 0x3F80u;
  r.u[1] = (t & 0x00040004u) * 0x0FE0u;
  r.u[2] = (t & 0x00100010u) * 0x03F8u;
  r.u[3] = (t & 0x00400040u) * 0x00FEu;
  return r.s;
}

// ---------------- kernel B1: 1024-thr, 1 block/CU, counted-vmcnt 3-buffer pipeline ----------------
// grid 256 (b=bid&7 XCD-pinned, 128-row panels). 16 waves = 4g x 4c:
// wave owns m1 fm-tiles {2g,2g+1} x fn {2c,2c+1}; m2 (fm2=w&7, kf2=w>>3).
// Stage: 1152 B-chunks + 128 mask-chunks; per-thread 1-2 loads/phase -> vmcnt(2)/(1).
__global__ __launch_bounds__(1024, 4) void kb1(const u16* __restrict__ H,
                                               const char* __restrict__ M1b,
                                               const char* __restrict__ M2b,
                                               const float* __restrict__ rs1, const float* __restrict__ rs2,
                                               const float* __restrict__ q1, const float* __restrict__ q2,
                                               const float* __restrict__ Wb, const float* __restrict__ bb,
                                               float* __restrict__ out) {
  __shared__ u16 bt[3][9216];              // 3-buffered B tile (54 KB)
  __shared__ u16 mkb[3][1024];             // 3-buffered mask slab (6 KB): [1024B m1][1024B m2]
  __shared__ float f2pf[2][128][16];       // m2@h2 kf-partials (16 KB)
  __shared__ u16 f2s[128 * 40];            // f2 bf16, K padded to 32 (10 KB)
  __shared__ u16 wb2s[4096];               // Wb2 padded to K=32 (8 KB)   -> 94 KB total

  const int tid = threadIdx.x;
  const int bid = blockIdx.x;
  const int b = bid & 7;
  const int i0 = (bid >> 3) * 128;

  const int w = tid >> 6, l = tid & 63, lr = l & 15, lg = l >> 4;
  const int g = w >> 2, c = w & 3;
  const int fm2 = w & 7, kf2 = w >> 3;
  const int lgsh = lg * 8;

  // B-chunk source offsets (u16 units within a kt-slab, b folded in)
  const uint32_t cA = tid, cB = 1024 + tid;
  const uint32_t offA = (cA < 576) ? (b * 4608 + cA * 8) : (36864 + b * 4608 + (cA - 576) * 8);
  const uint32_t offB = 36864 + b * 4608 + (cB - 576) * 8;   // cB always >= 1024 > 576
  // loop-carried source pointers (bumped per stage)
  const u16* pB1 = H + offA;
  const u16* pB2 = H + offB;                                  // used only tid<128
  const char* pM = (((tid & 64) ? M2b : M1b)) + (size_t)i0 * 8 + (size_t)(tid & 63) * 16; // tid in [128,256)
  const int d1 = tid * 16;
  const int d2 = 16384 + tid * 16;                            // tid<128
  const int dM = (tid - 128) * 16;                            // tid in [128,256)

#define STAGE(BUF) { \
    GLOAD16(pB1, (char*)&bt[BUF][0] + d1); \
    if (tid < 128) GLOAD16(pB2, (char*)&bt[BUF][0] + d2); \
    else if (tid < 256) GLOAD16(pM, (char*)&mkb[BUF][0] + dM); \
    pB1 += 73728; pB2 += 73728; pM += 32768; }

  // compute-phase LDS fragment offsets (u16)
  const int fA0 = (c * 2 + 0) * 512 + l * 8;
  const int fA1 = (c * 2 + 1) * 512 + l * 8;
  const int fB0 = 4608 + fA0;
  const int fB1 = 4608 + fA1;
  const int fM  = kf2 * 4608 + 4096 + l * 8;

  f32x4 zz = {0.f, 0.f, 0.f, 0.f};
  f32x4 acc00 = zz, acc01 = zz, acc10 = zz, acc11 = zz;
  f32x4 acc2 = zz;

#define WAITV { if (w < 4) asm volatile("s_waitcnt vmcnt(2)" ::: "memory"); \
                else asm volatile("s_waitcnt vmcnt(1)" ::: "memory"); }

#define COMPUTE(BUF) { \
    const u16* src_ = &bt[BUF][0]; \
    const char* mk_ = (const char*)&mkb[BUF][0]; \
    uint2 c0_ = *(const uint2*)(mk_ + ((g * 2 + 0) * 16 + lr) * 8); \
    uint2 c1_ = *(const uint2*)(mk_ + ((g * 2 + 1) * 16 + lr) * 8); \
    uint32_t c2_ = *(const uint32_t*)(mk_ + 1024 + (fm2 * 16 + lr) * 8 + kf2 * 4); \
    short8 bA0_ = *(const short8*)(src_ + fA0); \
    short8 bA1_ = *(const short8*)(src_ + fA1); \
    short8 bB0_ = *(const short8*)(src_ + fB0); \
    short8 bB1_ = *(const short8*)(src_ + fB1); \
    short8 bM_  = *(const short8*)(src_ + fM); \
    short8 e0x_ = expand_byte(c0_.x, lgsh), e0y_ = expand_byte(c0_.y, lgsh); \
    short8 e1x_ = expand_byte(c1_.x, lgsh), e1y_ = expand_byte(c1_.y, lgsh); \
    short8 e2v_ = expand_byte(c2_, lgsh); \
    __builtin_amdgcn_s_setprio(1); \
    acc00 = MFMA(e0x_, bA0_, acc00, 0, 0, 0); \
    acc01 = MFMA(e0x_, bA1_, acc01, 0, 0, 0); \
    acc00 = MFMA(e0y_, bB0_, acc00, 0, 0, 0); \
    acc01 = MFMA(e0y_, bB1_, acc01, 0, 0, 0); \
    acc10 = MFMA(e1x_, bA0_, acc10, 0, 0, 0); \
    acc11 = MFMA(e1x_, bA1_, acc11, 0, 0, 0); \
    acc10 = MFMA(e1y_, bB0_, acc10, 0, 0, 0); \
    acc11 = MFMA(e1y_, bB1_, acc11, 0, 0, 0); \
    acc2  = MFMA(e2v_, bM_, acc2, 0, 0, 0); \
    __builtin_amdgcn_s_setprio(0); }

#define PHASE(BUF, BUF2) { WAITV; __builtin_amdgcn_s_barrier(); STAGE(BUF2); COMPUTE(BUF) }

  // prologue: stage kt=0,1
  STAGE(0);
  STAGE(1);

  // stage Wb2 (overlaps prologue latency)
#pragma unroll
  for (int i = 0; i < 4; ++i) {
    int e = i * 1024 + tid;
    int r_ = e & 7, nn = (e >> 3) & 127, jb = e >> 10;
    int k = jb * 8 + r_;
    wb2s[e] = f2bf((k < 16) ? Wb[(128 + k) * 128 + nn] : 0.f);
  }

  for (int it = 0; it < 20; ++it) {        // phases 0..59
    PHASE(0, 2);
    PHASE(1, 0);
    PHASE(2, 1);
  }
  PHASE(0, 2);                             // phase 60 (stages slab 62)
  PHASE(1, 0);                             // phase 61 (stages slab 63)
  { WAITV; __builtin_amdgcn_s_barrier(); COMPUTE(2) }                          // phase 62
  { asm volatile("s_waitcnt vmcnt(0)" ::: "memory");
    __builtin_amdgcn_s_barrier(); COMPUTE(0) }                                 // phase 63

  // epilogue: combine m2 kf-partials -> f2 bf16 tile
#pragma unroll
  for (int gg = 0; gg < 4; ++gg)
    f2pf[kf2][fm2 * 16 + lg * 4 + gg][lr] = acc2[gg];
  __syncthreads();
#pragma unroll
  for (int j = 0; j < 2; ++j) {
    int e = j * 1024 + tid;                // 128x16 = 2048 elems
    int row = e >> 4, col = e & 15;
    f2s[row * 40 + col] = f2bf(f2pf[0][row][col] + f2pf[1][row][col]);
    f2s[row * 40 + 16 + col] = 0;
  }
  __syncthreads();

  // epilogue MFMA: acc[i][fj] += f2frag(fm=2g+i) x Wb2frag(fn=2c+fj)
  short8 bw0 = *(const short8*)(wb2s + ((lg * 128) + (c * 2 + 0) * 16 + lr) * 8);
  short8 bw1 = *(const short8*)(wb2s + ((lg * 128) + (c * 2 + 1) * 16 + lr) * 8);
  {
    short8 af0 = *(const short8*)(f2s + ((g * 2 + 0) * 16 + lr) * 40 + lg * 8);
    short8 af1 = *(const short8*)(f2s + ((g * 2 + 1) * 16 + lr) * 40 + lg * 8);
    acc00 = MFMA(af0, bw0, acc00, 0, 0, 0);
    acc01 = MFMA(af0, bw1, acc01, 0, 0, 0);
    acc10 = MFMA(af1, bw0, acc10, 0, 0, 0);
    acc11 = MFMA(af1, bw1, acc11, 0, 0, 0);
  }

  // final: + rs1*q1 + rs2*q2 + bb, store f32
  const int col0 = (c * 2 + 0) * 16 + lr, col1 = (c * 2 + 1) * 16 + lr;
  const float q10 = q1[col0], q20 = q2[col0], bb0 = bb[col0];
  const float q11 = q1[col1], q21 = q2[col1], bb1 = bb[col1];
#pragma unroll
  for (int i = 0; i < 2; ++i) {
    f32x4 a0 = i ? acc10 : acc00;
    f32x4 a1 = i ? acc11 : acc01;
#pragma unroll
    for (int gg = 0; gg < 4; ++gg) {
      int row = (g * 2 + i) * 16 + lg * 4 + gg;
      float r1 = rs1[i0 + row], r2 = rs2[i0 + row];
      size_t obase = ((size_t)b * 4096 + i0 + row) * 128;
      out[obase + col0] = a0[gg] + r1 * q10 + r2 * q20 + bb0;
      out[obase + col1] = a1[gg] + r1 * q11 + r2 * q21 + bb1;
    }
  }
}

extern "C" void kernel_launch(void* const* d_in, const int* in_sizes, int n_in,
                              void* d_out, int out_size, void* d_ws, size_t ws_size,
                              hipStream_t stream) {
  const float* x  = (const float*)d_in[0];
  const int*   sp = (const int*)d_in[1];
  const float* W1 = (const float*)d_in[2];
  const float* b1 = (const float*)d_in[3];
  const float* W2 = (const float*)d_in[4];
  const float* b2 = (const float*)d_in[5];
  const float* Wb = (const float*)d_in[6];
  const float* bb = (const float*)d_in[7];
  float* out = (float*)d_out;
  char* ws = (char*)d_ws;

  u16* H = (u16*)(ws + WS_H);
  float* q1 = (float*)(ws + WS_Q1);
  float* q2 = (float*)(ws + WS_Q2);
  unsigned long long* m1p = (unsigned long long*)(ws + WS_M1P);
  unsigned long long* m2p = (unsigned long long*)(ws + WS_M2P);
  float* rs1 = (float*)(ws + WS_RS1);
  float* rs2 = (float*)(ws + WS_RS2);
  u16* wsbg = (u16*)(ws + WS_WSB);

  k0<<<1088, 256, 0, stream>>>(sp, m1p, m2p, rs1, rs2, W1, Wb, b1, b2, W2, q1, q2, wsbg);
  kproj<<<256, 512, 0, stream>>>(x, wsbg, H);
  kb1<<<256, 1024, 0, stream>>>(H, (const char*)m1p, (const char*)m2p,
                                rs1, rs2, q1, q2, Wb, bb, out);
}